// Round 9
// baseline (212.482 us; speedup 1.0000x reference)
//
#include <hip/hip_runtime.h>
#include <math.h>

#define NB   4
#define NN   2048
#define DD   512
#define NOUT 512
#define NH   8
#define HDIM 64

typedef __attribute__((ext_vector_type(4))) short bf16x4;
typedef __attribute__((ext_vector_type(8))) short bf16x8;
typedef __attribute__((ext_vector_type(4))) float f32x4;
#define MFMA32(a, b, c)  __builtin_amdgcn_mfma_f32_16x16x32_bf16(a, b, c, 0, 0, 0)

typedef const __attribute__((address_space(1))) unsigned int* gas_ptr;
typedef __attribute__((address_space(3))) unsigned int* las_ptr;

#define SCALE2 0.18033688f   /* 8^-1 * log2(e) */

// Fragment-tiled layout: T[blk128][kstep32][row128][32k]
//   flat = blk*65536 + ks*4096 + r*32 + kk

__device__ inline unsigned short f2bf(float f) {
    unsigned int u = __float_as_uint(f);
    u += 0x7fffu + ((u >> 16) & 1u);   // RNE
    return (unsigned short)(u >> 16);
}

// pack two fp32 -> two bf16 (truncation) in ONE v_perm
__device__ inline unsigned int pack_trunc(float lo, float hi) {
    return __builtin_amdgcn_perm(__float_as_uint(hi), __float_as_uint(lo), 0x07060302u);
}

// ---------------------------------------------------------------------------
// prep: convx (x -> bf16 tiled), transW (weights -> bf16 transposed tiled),
// amask (adj -> u32 AND-words).
// ---------------------------------------------------------------------------
__global__ __launch_bounds__(256) void prep(
    const float* __restrict__ x, unsigned short* __restrict__ xt,
    const float* __restrict__ W0, const float* __restrict__ W1,
    const float* __restrict__ W2, const float* __restrict__ W3,
    unsigned short* __restrict__ Tqkv, unsigned short* __restrict__ To,
    const int* __restrict__ adj, unsigned int* __restrict__ amaskW)
{
    const int blk = blockIdx.x;
    const int t   = threadIdx.x;

    if (blk < 2048) {                       // ---- convx -> tiled ----
        const int i = (blk * 256 + t) * 8;
        const int m = i >> 9, k = i & 511;
        float4 a = *(const float4*)(x + i);
        float4 b = *(const float4*)(x + i + 4);
        ushort4 u0, u1;
        u0.x = f2bf(a.x); u0.y = f2bf(a.y); u0.z = f2bf(a.z); u0.w = f2bf(a.w);
        u1.x = f2bf(b.x); u1.y = f2bf(b.y); u1.z = f2bf(b.z); u1.w = f2bf(b.w);
        unsigned short* dst = xt + ((size_t)(m >> 7) * 65536)
                                 + (k >> 5) * 4096 + (m & 127) * 32 + (k & 31);
        *(ushort4*)dst       = u0;
        *(ushort4*)(dst + 4) = u1;
        return;
    }
    if (blk < 2304) {                       // ---- transW -> tiled ----
        __shared__ float tile[64][65];
        const int idx = blk - 2048;
        const int z = idx >> 6, rem = idx & 63;
        const float* W;
        switch (z) {
            case 0:  W = W0; break;
            case 1:  W = W1; break;
            case 2:  W = W2; break;
            default: W = W3; break;
        }
        unsigned short* T = (z < 3) ? Tqkv : To;
        const int ngbase  = (z < 3) ? z * 512 : 0;
        const int k0 = (rem & 7) * 64, n0 = (rem >> 3) * 64;
        const int r = t >> 6, c = t & 63;
#pragma unroll
        for (int rep = 0; rep < 16; ++rep) {
            const int row = rep * 4 + r;
            tile[row][c] = W[(size_t)(k0 + row) * NOUT + n0 + c];
        }
        __syncthreads();
        const int k  = k0 + c;
        const int ks = k >> 5, kk = k & 31;
#pragma unroll
        for (int rep = 0; rep < 16; ++rep) {
            const int row = rep * 4 + r;          // n within this matrix
            const int ng  = ngbase + n0 + row;
            T[((size_t)(ng >> 7) * 65536) + ks * 4096 + (ng & 127) * 32 + kk]
                = f2bf(tile[c][row]);
        }
        return;
    }
    // ---- amask: 4 u32 words (8 keys) per thread ----
    {
        const int gid  = (blk - 2304) * 256 + t;
        const int w0   = gid * 4;
        const int qrow = w0 >> 10;
        const int wloc = w0 & 1023;
        const int kb0  = wloc * 2;
        int4 a0 = *(const int4*)(adj + (size_t)qrow * NN + kb0);
        int4 a1 = *(const int4*)(adj + (size_t)qrow * NN + kb0 + 4);
        uint4 m;
        m.x = (a0.x ? 0xFFFFu : 0u) | (a0.y ? 0xFFFF0000u : 0u);
        m.y = (a0.z ? 0xFFFFu : 0u) | (a0.w ? 0xFFFF0000u : 0u);
        m.z = (a1.x ? 0xFFFFu : 0u) | (a1.y ? 0xFFFF0000u : 0u);
        m.w = (a1.z ? 0xFFFFu : 0u) | (a1.w ? 0xFFFF0000u : 0u);
        *(uint4*)(amaskW + (size_t)qrow * 1024 + wloc) = m;
    }
}

// ---------------------------------------------------------------------------
// Barrier-free LDS-free GEMM, fragment-tiled inputs, 128m x 64n tiles,
// depth-3 register pipeline (issue-to-use ~2 K-steps covers L2 latency).
// ---------------------------------------------------------------------------
#define GT_SETUP64()                                                           \
    const int t = threadIdx.x, wave = t >> 6, lane = t & 63;                   \
    const int quad = lane >> 4, l16 = lane & 15;                               \
    const int n0 = blockIdx.x * 64, m0 = blockIdx.y * 128;                     \
    const int wm = (wave & 1) * 64, wn = (wave >> 1) * 32;                     \
    const unsigned short* aP[4];                                               \
    const unsigned short* bP[2];                                               \
    _Pragma("unroll")                                                          \
    for (int mt = 0; mt < 4; ++mt)                                             \
        aP[mt] = Atil + (size_t)blockIdx.y * 65536                             \
               + (wm + mt * 16 + l16) * 32 + quad * 8;                         \
    _Pragma("unroll")                                                          \
    for (int nt = 0; nt < 2; ++nt) {                                           \
        const int ng = n0 + wn + nt * 16 + l16;                                \
        bP[nt] = Wtil + (size_t)(ng >> 7) * 65536 + (ng & 127) * 32 + quad * 8; \
    }

#define GT_LOADF(Af, Bf, ks)                                                   \
    _Pragma("unroll")                                                          \
    for (int mt = 0; mt < 4; ++mt) Af[mt] = *(const bf16x8*)(aP[mt] + (ks) * 4096); \
    _Pragma("unroll")                                                          \
    for (int nt = 0; nt < 2; ++nt) Bf[nt] = *(const bf16x8*)(bP[nt] + (ks) * 4096);

#define GT_MFMA(Af, Bf)                                                        \
    _Pragma("unroll")                                                          \
    for (int mt = 0; mt < 4; ++mt)                                             \
        _Pragma("unroll")                                                      \
        for (int nt = 0; nt < 2; ++nt)                                         \
            acc[mt][nt] = MFMA32(Af[mt], Bf[nt], acc[mt][nt]);

#define GT_LOOP3()                                                             \
    f32x4 acc[4][2];                                                           \
    _Pragma("unroll")                                                          \
    for (int mt = 0; mt < 4; ++mt)                                             \
        _Pragma("unroll")                                                      \
        for (int nt = 0; nt < 2; ++nt) acc[mt][nt] = (f32x4){0.f, 0.f, 0.f, 0.f}; \
    bf16x8 aS[3][4], bS[3][2];                                                 \
    GT_LOADF(aS[0], bS[0], 0);                                                 \
    GT_LOADF(aS[1], bS[1], 1);                                                 \
    _Pragma("unroll")                                                          \
    for (int kk = 0; kk < 16; ++kk) {                                          \
        if (kk < 14) { GT_LOADF(aS[(kk + 2) % 3], bS[(kk + 2) % 3], kk + 2); } \
        GT_MFMA(aS[kk % 3], bS[kk % 3]);                                       \
    }

// ---------------------------------------------------------------------------
// Fused QKV GEMM (1536 blocks). seg0 -> q (pre-scaled); seg1 -> k; seg2 -> v^T.
// ---------------------------------------------------------------------------
__global__ __launch_bounds__(256, 3) void gemm_qkv(
    const unsigned short* __restrict__ Atil,
    const unsigned short* __restrict__ Wtil,
    const float* __restrict__ bq, const float* __restrict__ bk,
    const float* __restrict__ bv,
    unsigned short* __restrict__ qo, unsigned short* __restrict__ ko,
    unsigned short* __restrict__ vto)
{
    __shared__ unsigned short eps[4 * 768];    // per-wave epilogue region
    GT_SETUP64();
    GT_LOOP3();

    const int seg   = n0 >> 9;           // 0:q 1:k 2:v
    const int nloc0 = n0 & 511;
    const float* bp = (seg == 0) ? bq : (seg == 1) ? bk : bv;
    unsigned short* dst3 = (seg == 0) ? qo : (seg == 1) ? ko : vto;
    const int h = (nloc0 + wn) >> 6;     // head for this wave's 32 cols

    float bias2[2];
#pragma unroll
    for (int nt = 0; nt < 2; ++nt) bias2[nt] = bp[nloc0 + wn + nt * 16 + l16];

    unsigned short* Lo = eps + wave * 768;
#pragma unroll
    for (int mt = 0; mt < 4; ++mt) {
        if (seg < 2) {
            // region [16 m][40 pad], then row-coalesced 16B stores
#pragma unroll
            for (int nt = 0; nt < 2; ++nt)
#pragma unroll
                for (int r = 0; r < 4; ++r) {
                    float val = acc[mt][nt][r] + bias2[nt];
                    if (seg == 0) val *= SCALE2;
                    Lo[(quad * 4 + r) * 40 + nt * 16 + l16] = f2bf(val);
                }
            const int row = lane >> 2;
            const int mg  = m0 + wm + mt * 16 + row;
            const int bb  = mg >> 11, n = mg & (NN - 1);
            bf16x8 v = *(const bf16x8*)&Lo[row * 40 + (lane & 3) * 8];
            *(bf16x8*)(dst3 + ((size_t)(bb * NH + h) * NN + n) * HDIM
                       + wn + (lane & 3) * 8) = v;
        } else {
            // region [32 d][24 pad], transposed -> d-row out
#pragma unroll
            for (int nt = 0; nt < 2; ++nt)
#pragma unroll
                for (int r = 0; r < 4; ++r) {
                    const float val = acc[mt][nt][r] + bias2[nt];
                    Lo[(nt * 16 + l16) * 24 + quad * 4 + r] = f2bf(val);
                }
            const int d  = lane >> 1;
            const int mg = m0 + wm + mt * 16;
            const int bb = mg >> 11, n = mg & (NN - 1);
            bf16x8 v = *(const bf16x8*)&Lo[d * 24 + (lane & 1) * 8];
            *(bf16x8*)(dst3 + ((size_t)(bb * NH + h) * HDIM + wn + d) * NN
                       + n + (lane & 1) * 8) = v;
        }
    }
}

// ---------------------------------------------------------------------------
// O-projection GEMM: 128x64 tiles (512 blocks), out fp32 [8192,512]
// ---------------------------------------------------------------------------
__global__ __launch_bounds__(256, 3) void gemm_o(
    const unsigned short* __restrict__ Atil,
    const unsigned short* __restrict__ Wtil,
    const float* __restrict__ bias,
    float* __restrict__ C)
{
    GT_SETUP64();
    GT_LOOP3();

    float bias2[2];
#pragma unroll
    for (int nt = 0; nt < 2; ++nt) bias2[nt] = bias[n0 + wn + nt * 16 + l16];

#pragma unroll
    for (int mt = 0; mt < 4; ++mt)
#pragma unroll
        for (int nt = 0; nt < 2; ++nt) {
            const int col = n0 + wn + nt * 16 + l16;
#pragma unroll
            for (int r = 0; r < 4; ++r) {
                const int row = m0 + wm + mt * 16 + quad * 4 + r;
                C[(size_t)row * NOUT + col] = acc[mt][nt][r] + bias2[nt];
            }
        }
}

// ---------------------------------------------------------------------------
// MFMA flash attention — all-K=32, TWO Q-groups per wave (32 queries/wave):
// every K/V fragment read from LDS feeds both groups, halving LDS bytes per
// query (the round-8 bottleneck). 4 waves/block, 128 q/block, grid 512.
// ---------------------------------------------------------------------------
__global__ __launch_bounds__(256, 2) void attn_mfma(
    const unsigned short* __restrict__ qg,
    const unsigned short* __restrict__ kg,
    const unsigned short* __restrict__ vt,
    const unsigned int* __restrict__ amask,   // [q][1024] u32 AND-words
    unsigned short* __restrict__ aot)
{
    __shared__ unsigned short smem[4 * 64 * 64];   // Ka | Va | Kb | Vb (32 KB)
    unsigned short* Ka = smem;
    unsigned short* Va = smem + 4096;
    unsigned short* Kb = smem + 8192;
    unsigned short* Vb = smem + 12288;

    const int t    = threadIdx.x;
    const int wave = t >> 6;     // 0..3
    const int lane = t & 63;
    const int quad = lane >> 4;
    const int l16  = lane & 15;

    const int qt = blockIdx.x, h = blockIdx.y, b = blockIdx.z;
    const int bh = b * NH + h;
    const int q0 = qt * 128;

    const unsigned short* kbase  = kg + (size_t)bh * NN * HDIM;
    const unsigned short* vtbase = vt + (size_t)bh * HDIM * NN;

    // DMA swizzle (16B blocks): physical blk = logical blk ^ (row & 7)
    const int drow = lane >> 3;
    const int dblk = (lane & 7) ^ drow;

    // fragment-read swizzle offsets
    const int sw  = l16 & 7;
    const int bo0 = (quad ^ sw) * 8;
    const int bo1 = bo0 ^ 32;

    // each wave stages 16 rows (2 DMA pairs)
#define ATT_ISSUE(kt, Kd, Vd)                                                  \
    _Pragma("unroll")                                                          \
    for (int c = 0; c < 2; ++c) {                                              \
        const int r0 = wave * 16 + c * 8;                                      \
        const int p  = r0 + drow;                                              \
        const int Lp = (p & 32) + ((p >> 2) & 3) * 8 + ((p >> 4) & 1) * 4 + (p & 3); \
        __builtin_amdgcn_global_load_lds(                                      \
            (gas_ptr)(kbase + (size_t)((kt) * 64 + Lp) * HDIM + dblk * 8),     \
            (las_ptr)(Kd + r0 * 64), 16, 0, 0);                                \
        __builtin_amdgcn_global_load_lds(                                      \
            (gas_ptr)(vtbase + (size_t)p * NN + (kt) * 64 + dblk * 8),         \
            (las_ptr)(Vd + r0 * 64), 16, 0, 0);                                \
    }

    // Q B-fragments for both groups (row = lane's query)
    const int myq0 = q0 + wave * 32 + l16;
    const int myq1 = myq0 + 16;
    const unsigned short* qr0 = qg + ((size_t)bh * NN + myq0) * HDIM;
    const unsigned short* qr1 = qg + ((size_t)bh * NN + myq1) * HDIM;
    bf16x8 bQ0[2], bQ1[2];
    bQ0[0] = *(const bf16x8*)(qr0 + quad * 8);
    bQ1[0] = *(const bf16x8*)(qr0 + quad * 8 + 32);
    bQ0[1] = *(const bf16x8*)(qr1 + quad * 8);
    bQ1[1] = *(const bf16x8*)(qr1 + quad * 8 + 32);

    const unsigned int* mrow[2] = {
        amask + (size_t)myq0 * 1024 + quad * 4,
        amask + (size_t)myq1 * 1024 + quad * 4 };

#define MLOADG(dst, kt)                                                        \
    _Pragma("unroll")                                                          \
    for (int g = 0; g < 2; ++g)                                                \
        _Pragma("unroll")                                                      \
        for (int c = 0; c < 2; ++c)                                            \
            dst[g * 2 + c] = *(const uint4*)(mrow[g] + (kt) * 32 + c * 16);

    bf16x8 ones8;
#pragma unroll
    for (int j = 0; j < 8; ++j) ones8[j] = (short)0x3F80;

    f32x4 O[2][4];
#pragma unroll
    for (int g = 0; g < 2; ++g)
#pragma unroll
        for (int dt = 0; dt < 4; ++dt) O[g][dt] = (f32x4){0.f, 0.f, 0.f, 0.f};
    f32x4 lacc[2];
    lacc[0] = (f32x4){0.f, 0.f, 0.f, 0.f};
    lacc[1] = (f32x4){0.f, 0.f, 0.f, 0.f};

    auto tile = [&](const unsigned short* Ks, const unsigned short* Vs,
                    const uint4* mw) {
        union { unsigned int u[2][4]; bf16x8 v[2]; } P[2];   // [g] -> chunk c
#pragma unroll
        for (int nt = 0; nt < 4; ++nt) {
            bf16x8 aK0 = *(const bf16x8*)&Ks[(nt * 16 + l16) * 64 + bo0];
            bf16x8 aK1 = *(const bf16x8*)&Ks[(nt * 16 + l16) * 64 + bo1];
            const int c = nt >> 1, half = nt & 1;
#pragma unroll
            for (int g = 0; g < 2; ++g) {
                f32x4 s = (f32x4){0.f, 0.f, 0.f, 0.f};
                s = MFMA32(aK0, bQ0[g], s);
                s = MFMA32(aK1, bQ1[g], s);
                const float p0 = exp2f(s[0]);
                const float p1 = exp2f(s[1]);
                const float p2 = exp2f(s[2]);
                const float p3 = exp2f(s[3]);
                const uint4 m = mw[g * 2 + c];
                P[g].u[c][half * 2 + 0] = pack_trunc(p0, p1) & (half ? m.z : m.x);
                P[g].u[c][half * 2 + 1] = pack_trunc(p2, p3) & (half ? m.w : m.y);
            }
        }
#pragma unroll
        for (int g = 0; g < 2; ++g) {
            lacc[g] = MFMA32(ones8, P[g].v[0], lacc[g]);
            lacc[g] = MFMA32(ones8, P[g].v[1], lacc[g]);
        }
#pragma unroll
        for (int dt = 0; dt < 4; ++dt)
#pragma unroll
            for (int c = 0; c < 2; ++c) {
                bf16x8 aV = *(const bf16x8*)
                    &Vs[(dt * 16 + l16) * 64 + (((c * 4 + quad) ^ sw) * 8)];
#pragma unroll
                for (int g = 0; g < 2; ++g)
                    O[g][dt] = MFMA32(aV, P[g].v[c], O[g][dt]);
            }
    };

    uint4 mA[4], mB[4];
    MLOADG(mA, 0);
    ATT_ISSUE(0, Ka, Va);
    for (int kk = 0; kk < 16; ++kk) {
        __syncthreads();
        ATT_ISSUE(2 * kk + 1, Kb, Vb);
        MLOADG(mB, 2 * kk + 1);
        tile(Ka, Va, mA);
        __syncthreads();
        if (kk < 15) {
            ATT_ISSUE(2 * kk + 2, Ka, Va);
            MLOADG(mA, 2 * kk + 2);
        }
        tile(Kb, Vb, mB);
    }
    __syncthreads();   // all waves done with K/V buffers

    // ---- epilogue: per group, O^T -> per-wave LDS -> fragment-tiled out ----
    unsigned short* Lo = smem + wave * (16 * 72);
#pragma unroll
    for (int g = 0; g < 2; ++g) {
        const float inv = 1.f / lacc[g][0];
#pragma unroll
        for (int dt = 0; dt < 4; ++dt) {
            const float v0 = O[g][dt][0] * inv, v1 = O[g][dt][1] * inv;
            const float v2 = O[g][dt][2] * inv, v3 = O[g][dt][3] * inv;
            *(unsigned int*)&Lo[l16 * 72 + dt * 16 + quad * 4]     = pack_trunc(v0, v1);
            *(unsigned int*)&Lo[l16 * 72 + dt * 16 + quad * 4 + 2] = pack_trunc(v2, v3);
        }
        const int rr = lane >> 2;
        const int qq = q0 + wave * 32 + g * 16 + rr;
        const int m  = b * NN + qq;
        const int mb = m >> 7, r = m & 127;
#pragma unroll
        for (int i = 0; i < 2; ++i) {
            const int ch = (lane & 3) + 4 * i;
            const int ks = h * 2 + (ch >> 2);
            bf16x8 val = *(const bf16x8*)&Lo[rr * 72 + ch * 8];
            *(bf16x8*)(aot + (size_t)mb * 65536 + ks * 4096 + r * 32 + (ch & 3) * 8) = val;
        }
    }
#undef ATT_ISSUE
#undef MLOADG
}

// ---------------------------------------------------------------------------
extern "C" void kernel_launch(void* const* d_in, const int* in_sizes, int n_in,
                              void* d_out, int out_size, void* d_ws, size_t ws_size,
                              hipStream_t stream)
{
    const float* x   = (const float*)d_in[0];
    const int*   adj = (const int*)  d_in[1];
    const float* Wq  = (const float*)d_in[2];
    const float* bq  = (const float*)d_in[3];
    const float* Wk  = (const float*)d_in[4];
    const float* bk  = (const float*)d_in[5];
    const float* Wv  = (const float*)d_in[6];
    const float* bv  = (const float*)d_in[7];
    const float* Wo  = (const float*)d_in[8];
    const float* bo  = (const float*)d_in[9];
    float* out = (float*)d_out;

    const size_t qkv_elems = (size_t)NB * NH * NN * HDIM;   // 4,194,304
    unsigned short* xt    = (unsigned short*)d_ws;           // x tiled; reused as aot
    unsigned short* q     = xt   + qkv_elems;
    unsigned short* kb    = q    + qkv_elems;
    unsigned short* vtb   = kb   + qkv_elems;
    unsigned short* tWqkv = vtb  + qkv_elems;                // 1536x512 tiled
    unsigned short* tWo   = tWqkv + (size_t)3 * DD * NOUT;   // 512x512 tiled
    unsigned int*   amaskW = (unsigned int*)(tWo + (size_t)DD * NOUT);  // 8MB
    unsigned short* aot   = xt;                              // alias (xt dead after QKV)

    prep<<<dim3(4352), 256, 0, stream>>>(x, xt, Wq, Wk, Wv, Wo,
                                         tWqkv, tWo, adj, amaskW);

    gemm_qkv<<<dim3(24, 64), 256, 0, stream>>>(xt, tWqkv, bq, bk, bv, q, kb, vtb);

    attn_mfma<<<dim3(NN / 128, NH, NB), 256, 0, stream>>>(q, kb, vtb, amaskW, aot);

    gemm_o<<<dim3(8, 64), 256, 0, stream>>>(aot, tWo, bo, out);
}

// Round 10
// 195.890 us; speedup vs baseline: 1.0847x; 1.0847x over previous
//
#include <hip/hip_runtime.h>
#include <math.h>

#define NB   4
#define NN   2048
#define DD   512
#define NOUT 512
#define NH   8
#define HDIM 64

typedef __attribute__((ext_vector_type(4))) short bf16x4;
typedef __attribute__((ext_vector_type(8))) short bf16x8;
typedef __attribute__((ext_vector_type(4))) float f32x4;
#define MFMA32(a, b, c)  __builtin_amdgcn_mfma_f32_16x16x32_bf16(a, b, c, 0, 0, 0)

typedef const __attribute__((address_space(1))) unsigned int* gas_ptr;
typedef __attribute__((address_space(3))) unsigned int* las_ptr;

#define SCALE2 0.18033688f   /* 8^-1 * log2(e) */

// Fragment-tiled layout: T[blk128][kstep32][row128][32k]
//   flat = blk*65536 + ks*4096 + r*32 + kk

__device__ inline unsigned short f2bf(float f) {
    unsigned int u = __float_as_uint(f);
    u += 0x7fffu + ((u >> 16) & 1u);   // RNE
    return (unsigned short)(u >> 16);
}

// pack two fp32 -> two bf16 (truncation) in ONE v_perm
__device__ inline unsigned int pack_trunc(float lo, float hi) {
    return __builtin_amdgcn_perm(__float_as_uint(hi), __float_as_uint(lo), 0x07060302u);
}

// ---------------------------------------------------------------------------
// prep: convx (x -> bf16 tiled), transW (weights -> bf16 transposed tiled),
// amask (adj -> u32 AND-words).
// ---------------------------------------------------------------------------
__global__ __launch_bounds__(256) void prep(
    const float* __restrict__ x, unsigned short* __restrict__ xt,
    const float* __restrict__ W0, const float* __restrict__ W1,
    const float* __restrict__ W2, const float* __restrict__ W3,
    unsigned short* __restrict__ Tqkv, unsigned short* __restrict__ To,
    const int* __restrict__ adj, unsigned int* __restrict__ amaskW)
{
    const int blk = blockIdx.x;
    const int t   = threadIdx.x;

    if (blk < 2048) {                       // ---- convx -> tiled ----
        const int i = (blk * 256 + t) * 8;
        const int m = i >> 9, k = i & 511;
        float4 a = *(const float4*)(x + i);
        float4 b = *(const float4*)(x + i + 4);
        ushort4 u0, u1;
        u0.x = f2bf(a.x); u0.y = f2bf(a.y); u0.z = f2bf(a.z); u0.w = f2bf(a.w);
        u1.x = f2bf(b.x); u1.y = f2bf(b.y); u1.z = f2bf(b.z); u1.w = f2bf(b.w);
        unsigned short* dst = xt + ((size_t)(m >> 7) * 65536)
                                 + (k >> 5) * 4096 + (m & 127) * 32 + (k & 31);
        *(ushort4*)dst       = u0;
        *(ushort4*)(dst + 4) = u1;
        return;
    }
    if (blk < 2304) {                       // ---- transW -> tiled ----
        __shared__ float tile[64][65];
        const int idx = blk - 2048;
        const int z = idx >> 6, rem = idx & 63;
        const float* W;
        switch (z) {
            case 0:  W = W0; break;
            case 1:  W = W1; break;
            case 2:  W = W2; break;
            default: W = W3; break;
        }
        unsigned short* T = (z < 3) ? Tqkv : To;
        const int ngbase  = (z < 3) ? z * 512 : 0;
        const int k0 = (rem & 7) * 64, n0 = (rem >> 3) * 64;
        const int r = t >> 6, c = t & 63;
#pragma unroll
        for (int rep = 0; rep < 16; ++rep) {
            const int row = rep * 4 + r;
            tile[row][c] = W[(size_t)(k0 + row) * NOUT + n0 + c];
        }
        __syncthreads();
        const int k  = k0 + c;
        const int ks = k >> 5, kk = k & 31;
#pragma unroll
        for (int rep = 0; rep < 16; ++rep) {
            const int row = rep * 4 + r;          // n within this matrix
            const int ng  = ngbase + n0 + row;
            T[((size_t)(ng >> 7) * 65536) + ks * 4096 + (ng & 127) * 32 + kk]
                = f2bf(tile[c][row]);
        }
        return;
    }
    // ---- amask: 4 u32 words (8 keys) per thread ----
    {
        const int gid  = (blk - 2304) * 256 + t;
        const int w0   = gid * 4;
        const int qrow = w0 >> 10;
        const int wloc = w0 & 1023;
        const int kb0  = wloc * 2;
        int4 a0 = *(const int4*)(adj + (size_t)qrow * NN + kb0);
        int4 a1 = *(const int4*)(adj + (size_t)qrow * NN + kb0 + 4);
        uint4 m;
        m.x = (a0.x ? 0xFFFFu : 0u) | (a0.y ? 0xFFFF0000u : 0u);
        m.y = (a0.z ? 0xFFFFu : 0u) | (a0.w ? 0xFFFF0000u : 0u);
        m.z = (a1.x ? 0xFFFFu : 0u) | (a1.y ? 0xFFFF0000u : 0u);
        m.w = (a1.z ? 0xFFFFu : 0u) | (a1.w ? 0xFFFF0000u : 0u);
        *(uint4*)(amaskW + (size_t)qrow * 1024 + wloc) = m;
    }
}

// ---------------------------------------------------------------------------
// Barrier-free LDS-free GEMM on fragment-tiled inputs, 128x128 tiles,
// depth-3 register pipeline: per K-step 16 MFMA (~78cyc), issue-to-use
// ~2 steps (~156cyc) covers L2 latency.
// ---------------------------------------------------------------------------
#define GT_SETUP()                                                             \
    const int t = threadIdx.x, wave = t >> 6, lane = t & 63;                   \
    const int quad = lane >> 4, l16 = lane & 15;                               \
    const int n0 = blockIdx.x * 128, m0 = blockIdx.y * 128;                    \
    const int wm = (wave & 1) * 64, wn = (wave >> 1) * 64;                     \
    const unsigned short* aP[4];                                               \
    const unsigned short* bP[4];                                               \
    _Pragma("unroll")                                                          \
    for (int mt = 0; mt < 4; ++mt)                                             \
        aP[mt] = Atil + (size_t)blockIdx.y * 65536                             \
               + (wm + mt * 16 + l16) * 32 + quad * 8;                         \
    _Pragma("unroll")                                                          \
    for (int nt = 0; nt < 4; ++nt)                                             \
        bP[nt] = Wtil + (size_t)blockIdx.x * 65536                             \
               + (wn + nt * 16 + l16) * 32 + quad * 8;

#define GT_LOADF(Af, Bf, NTC, ks)                                              \
    _Pragma("unroll")                                                          \
    for (int mt = 0; mt < 4; ++mt) Af[mt] = *(const bf16x8*)(aP[mt] + (ks) * 4096); \
    _Pragma("unroll")                                                          \
    for (int nt = 0; nt < NTC; ++nt) Bf[nt] = *(const bf16x8*)(bP[nt] + (ks) * 4096);

#define GT_MFMA(Af, Bf, NTC)                                                   \
    _Pragma("unroll")                                                          \
    for (int mt = 0; mt < 4; ++mt)                                             \
        _Pragma("unroll")                                                      \
        for (int nt = 0; nt < NTC; ++nt)                                       \
            acc[mt][nt] = MFMA32(Af[mt], Bf[nt], acc[mt][nt]);

// depth-3, NTC=4 (gemm_qkv)
#define GT_LOOP3_4()                                                           \
    f32x4 acc[4][4];                                                           \
    _Pragma("unroll")                                                          \
    for (int mt = 0; mt < 4; ++mt)                                             \
        _Pragma("unroll")                                                      \
        for (int nt = 0; nt < 4; ++nt) acc[mt][nt] = (f32x4){0.f, 0.f, 0.f, 0.f}; \
    bf16x8 aS[3][4], bS[3][4];                                                 \
    GT_LOADF(aS[0], bS[0], 4, 0);                                              \
    GT_LOADF(aS[1], bS[1], 4, 1);                                              \
    _Pragma("unroll")                                                          \
    for (int kk = 0; kk < 16; ++kk) {                                          \
        if (kk < 14) { GT_LOADF(aS[(kk + 2) % 3], bS[(kk + 2) % 3], 4, kk + 2); } \
        GT_MFMA(aS[kk % 3], bS[kk % 3], 4);                                    \
    }

// depth-4, NTC=2 (gemm_o, 128x64 tiles)
#define GT_LOOP4_2()                                                           \
    f32x4 acc[4][2];                                                           \
    _Pragma("unroll")                                                          \
    for (int mt = 0; mt < 4; ++mt)                                             \
        _Pragma("unroll")                                                      \
        for (int nt = 0; nt < 2; ++nt) acc[mt][nt] = (f32x4){0.f, 0.f, 0.f, 0.f}; \
    bf16x8 aS[4][4], bS[4][2];                                                 \
    GT_LOADF(aS[0], bS[0], 2, 0);                                              \
    GT_LOADF(aS[1], bS[1], 2, 1);                                              \
    GT_LOADF(aS[2], bS[2], 2, 2);                                              \
    _Pragma("unroll")                                                          \
    for (int kk = 0; kk < 16; ++kk) {                                          \
        if (kk < 13) { GT_LOADF(aS[(kk + 3) & 3], bS[(kk + 3) & 3], 2, kk + 3); } \
        GT_MFMA(aS[kk & 3], bS[kk & 3], 2);                                    \
    }

// ---------------------------------------------------------------------------
// Fused QKV GEMM (768 blocks). Coalesced epilogue via per-wave LDS.
// seg0 -> q bf16 [B,H,N,64] pre-scaled by SCALE2; seg1 -> k; seg2 -> v^T.
// ---------------------------------------------------------------------------
__global__ __launch_bounds__(256, 2) void gemm_qkv(
    const unsigned short* __restrict__ Atil,
    const unsigned short* __restrict__ Wtil,
    const float* __restrict__ bq, const float* __restrict__ bk,
    const float* __restrict__ bv,
    unsigned short* __restrict__ qo, unsigned short* __restrict__ ko,
    unsigned short* __restrict__ vto)
{
    __shared__ unsigned short eps[4 * 2560];   // per-wave epilogue region
    GT_SETUP();
    GT_LOOP3_4();

    const int seg   = n0 >> 9;           // 0:q 1:k 2:v
    const int nloc0 = n0 & 511;
    const float* bp = (seg == 0) ? bq : (seg == 1) ? bk : bv;
    unsigned short* dst3 = (seg == 0) ? qo : (seg == 1) ? ko : vto;
    const int h = (nloc0 + wn) >> 6;     // wave's 64 cols = one head

    float bias4[4];
#pragma unroll
    for (int nt = 0; nt < 4; ++nt) bias4[nt] = bp[nloc0 + wn + nt * 16 + l16];

    unsigned short* Lo = eps + wave * 2560;
#pragma unroll
    for (int mt = 0; mt < 4; ++mt) {
        if (seg < 2) {
            // region [16 m][72 d-pad], C-layout scatter -> row-coalesced out
#pragma unroll
            for (int nt = 0; nt < 4; ++nt)
#pragma unroll
                for (int r = 0; r < 4; ++r) {
                    float val = acc[mt][nt][r] + bias4[nt];
                    if (seg == 0) val *= SCALE2;
                    Lo[(quad * 4 + r) * 72 + nt * 16 + l16] = f2bf(val);
                }
#pragma unroll
            for (int pass = 0; pass < 2; ++pass) {
                const int row = pass * 8 + (lane >> 3);
                const int mg  = m0 + wm + mt * 16 + row;
                const int bb  = mg >> 11, n = mg & (NN - 1);
                bf16x8 v = *(const bf16x8*)&Lo[row * 72 + (lane & 7) * 8];
                *(bf16x8*)(dst3 + ((size_t)(bb * NH + h) * NN + n) * HDIM
                           + (lane & 7) * 8) = v;
            }
        } else {
            // region [64 d][40-pad m], transposed scatter -> d-row out
#pragma unroll
            for (int nt = 0; nt < 4; ++nt)
#pragma unroll
                for (int r = 0; r < 4; ++r) {
                    const float val = acc[mt][nt][r] + bias4[nt];
                    Lo[(nt * 16 + l16) * 40 + quad * 4 + r] = f2bf(val);
                }
            const int d  = lane;
            const int mg = m0 + wm + mt * 16;
            const int bb = mg >> 11, n = mg & (NN - 1);
            unsigned short* dr = dst3 + ((size_t)(bb * NH + h) * HDIM + d) * NN + n;
            *(bf16x8*)dr       = *(const bf16x8*)&Lo[d * 40];
            *(bf16x8*)(dr + 8) = *(const bf16x8*)&Lo[d * 40 + 8];
        }
    }
}

// ---------------------------------------------------------------------------
// O-projection GEMM: 128x64 tiles (512 blocks), depth-4, out fp32 [8192,512]
// ---------------------------------------------------------------------------
__global__ __launch_bounds__(256, 3) void gemm_o(
    const unsigned short* __restrict__ Atil,
    const unsigned short* __restrict__ Wtil,
    const float* __restrict__ bias,
    float* __restrict__ C)
{
    const int t = threadIdx.x, wave = t >> 6, lane = t & 63;
    const int quad = lane >> 4, l16 = lane & 15;
    const int n0 = blockIdx.x * 64, m0 = blockIdx.y * 128;
    const int wm = (wave & 1) * 64, wn = (wave >> 1) * 32;
    const unsigned short* aP[4];
    const unsigned short* bP[2];
#pragma unroll
    for (int mt = 0; mt < 4; ++mt)
        aP[mt] = Atil + (size_t)blockIdx.y * 65536
               + (wm + mt * 16 + l16) * 32 + quad * 8;
#pragma unroll
    for (int nt = 0; nt < 2; ++nt) {
        const int ng = n0 + wn + nt * 16 + l16;
        bP[nt] = Wtil + (size_t)(ng >> 7) * 65536 + (ng & 127) * 32 + quad * 8;
    }

    GT_LOOP4_2();

    float bias2[2];
#pragma unroll
    for (int nt = 0; nt < 2; ++nt) bias2[nt] = bias[n0 + wn + nt * 16 + l16];

#pragma unroll
    for (int mt = 0; mt < 4; ++mt)
#pragma unroll
        for (int nt = 0; nt < 2; ++nt) {
            const int col = n0 + wn + nt * 16 + l16;
#pragma unroll
            for (int r = 0; r < 4; ++r) {
                const int row = m0 + wm + mt * 16 + quad * 4 + r;
                C[(size_t)row * NOUT + col] = acc[mt][nt][r] + bias2[nt];
            }
        }
}

// ---------------------------------------------------------------------------
// MFMA flash attention — all-K=32 via key permutation (round-8 proven form).
// 8 waves/block, 16 q/wave, grid 512. P^T registers feed mfma32 B operand
// directly; masking = one v_and per packed pair; lsum via MFMA(ones, P).
// ---------------------------------------------------------------------------
__global__ __launch_bounds__(512) void attn_mfma(
    const unsigned short* __restrict__ qg,
    const unsigned short* __restrict__ kg,
    const unsigned short* __restrict__ vt,
    const unsigned int* __restrict__ amask,   // [q][1024] u32 AND-words
    unsigned short* __restrict__ aot)
{
    __shared__ unsigned short smem[4 * 64 * 64];   // Ka | Va | Kb | Vb (32 KB)
    unsigned short* Ka = smem;
    unsigned short* Va = smem + 4096;
    unsigned short* Kb = smem + 8192;
    unsigned short* Vb = smem + 12288;

    const int t    = threadIdx.x;
    const int wave = t >> 6;
    const int lane = t & 63;
    const int quad = lane >> 4;
    const int l16  = lane & 15;

    const int qt = blockIdx.x, h = blockIdx.y, b = blockIdx.z;
    const int bh = b * NH + h;
    const int q0 = qt * 128;

    const unsigned short* kbase  = kg + (size_t)bh * NN * HDIM;
    const unsigned short* vtbase = vt + (size_t)bh * HDIM * NN;

    // DMA swizzle (16B blocks): physical blk = logical blk ^ (row & 7)
    const int drow = lane >> 3;
    const int dblk = (lane & 7) ^ drow;
    // key permutation: physical LDS row p holds logical key L(p)
    const int p  = wave * 8 + drow;
    const int Lp = (p & 32) + ((p >> 2) & 3) * 8 + ((p >> 4) & 1) * 4 + (p & 3);

    // fragment-read swizzle offsets
    const int sw  = l16 & 7;
    const int bo0 = (quad ^ sw) * 8;         // K d-chunk0 (16B)
    const int bo1 = bo0 ^ 32;                // K d-chunk1

#define ATT_ISSUE(kt, Kd, Vd)                                                  \
    {                                                                          \
        const int r0 = wave * 8;                                               \
        __builtin_amdgcn_global_load_lds(                                      \
            (gas_ptr)(kbase + (size_t)((kt) * 64 + Lp) * HDIM + dblk * 8),     \
            (las_ptr)(Kd + r0 * 64), 16, 0, 0);                                \
        __builtin_amdgcn_global_load_lds(                                      \
            (gas_ptr)(vtbase + (size_t)(r0 + drow) * NN + (kt) * 64 + dblk * 8), \
            (las_ptr)(Vd + r0 * 64), 16, 0, 0);                                \
    }

    // Q B-fragments straight from global (row = this lane's query)
    const int myq = q0 + wave * 16 + l16;
    const unsigned short* qrow = qg + ((size_t)bh * NN + myq) * HDIM;
    const bf16x8 bQ0 = *(const bf16x8*)(qrow + quad * 8);
    const bf16x8 bQ1 = *(const bf16x8*)(qrow + quad * 8 + 32);

    const unsigned int* mrow = amask + (size_t)myq * 1024 + quad * 4;
#define MLOAD(kt, c) (*(const uint4*)(mrow + (kt) * 32 + (c) * 16))

    bf16x8 ones8;
#pragma unroll
    for (int j = 0; j < 8; ++j) ones8[j] = (short)0x3F80;

    f32x4 O[4];
#pragma unroll
    for (int dt = 0; dt < 4; ++dt) O[dt] = (f32x4){0.f, 0.f, 0.f, 0.f};
    f32x4 lacc = (f32x4){0.f, 0.f, 0.f, 0.f};

    auto tile = [&](const unsigned short* Ks, const unsigned short* Vs,
                    uint4 mw0, uint4 mw1) {
        bf16x8 Pt[2];
#pragma unroll
        for (int c = 0; c < 2; ++c) {
            const uint4 mw = c ? mw1 : mw0;
            union { unsigned int u[4]; bf16x8 v; } cv;
#pragma unroll
            for (int half = 0; half < 2; ++half) {
                const int nt = c * 2 + half;
                bf16x8 aK0 = *(const bf16x8*)&Ks[(nt * 16 + l16) * 64 + bo0];
                bf16x8 aK1 = *(const bf16x8*)&Ks[(nt * 16 + l16) * 64 + bo1];
                f32x4 s = (f32x4){0.f, 0.f, 0.f, 0.f};
                s = MFMA32(aK0, bQ0, s);
                s = MFMA32(aK1, bQ1, s);
                const float p0 = exp2f(s[0]);
                const float p1 = exp2f(s[1]);
                const float p2 = exp2f(s[2]);
                const float p3 = exp2f(s[3]);
                cv.u[half * 2 + 0] = pack_trunc(p0, p1) & (half ? mw.z : mw.x);
                cv.u[half * 2 + 1] = pack_trunc(p2, p3) & (half ? mw.w : mw.y);
            }
            Pt[c] = cv.v;
            lacc = MFMA32(ones8, Pt[c], lacc);
        }
#pragma unroll
        for (int dt = 0; dt < 4; ++dt)
#pragma unroll
            for (int c = 0; c < 2; ++c) {
                bf16x8 aV = *(const bf16x8*)
                    &Vs[(dt * 16 + l16) * 64 + (((c * 4 + quad) ^ sw) * 8)];
                O[dt] = MFMA32(aV, Pt[c], O[dt]);
            }
    };

    uint4 mA0 = MLOAD(0, 0), mA1 = MLOAD(0, 1);
    uint4 mB0, mB1;
    ATT_ISSUE(0, Ka, Va);
    for (int kk = 0; kk < 16; ++kk) {
        __syncthreads();
        ATT_ISSUE(2 * kk + 1, Kb, Vb);
        mB0 = MLOAD(2 * kk + 1, 0); mB1 = MLOAD(2 * kk + 1, 1);
        tile(Ka, Va, mA0, mA1);
        __syncthreads();
        if (kk < 15) {
            ATT_ISSUE(2 * kk + 2, Ka, Va);
            mA0 = MLOAD(2 * kk + 2, 0); mA1 = MLOAD(2 * kk + 2, 1);
        }
        tile(Kb, Vb, mB0, mB1);
    }
    __syncthreads();   // all waves done reading K/V buffers

    // ---- epilogue: O^T -> per-wave LDS region -> fragment-tiled bf16 out ----
    const float inv = 1.f / lacc[0];
    unsigned short* Lo = smem + wave * (16 * 72);
#pragma unroll
    for (int dt = 0; dt < 4; ++dt) {
        const float v0 = O[dt][0] * inv, v1 = O[dt][1] * inv;
        const float v2 = O[dt][2] * inv, v3 = O[dt][3] * inv;
        *(unsigned int*)&Lo[l16 * 72 + dt * 16 + quad * 4]     = pack_trunc(v0, v1);
        *(unsigned int*)&Lo[l16 * 72 + dt * 16 + quad * 4 + 2] = pack_trunc(v2, v3);
    }
    const int rr = lane >> 2;
    const int qq = q0 + wave * 16 + rr;
    const int m  = b * NN + qq;
    const int mb = m >> 7, r = m & 127;
#pragma unroll
    for (int i = 0; i < 2; ++i) {
        const int ch = (lane & 3) + 4 * i;            // 0..7 (d = ch*8)
        const int ks = h * 2 + (ch >> 2);
        bf16x8 val = *(const bf16x8*)&Lo[rr * 72 + ch * 8];
        *(bf16x8*)(aot + (size_t)mb * 65536 + ks * 4096 + r * 32 + (ch & 3) * 8) = val;
    }
#undef ATT_ISSUE
#undef MLOAD
}

// ---------------------------------------------------------------------------
extern "C" void kernel_launch(void* const* d_in, const int* in_sizes, int n_in,
                              void* d_out, int out_size, void* d_ws, size_t ws_size,
                              hipStream_t stream)
{
    const float* x   = (const float*)d_in[0];
    const int*   adj = (const int*)  d_in[1];
    const float* Wq  = (const float*)d_in[2];
    const float* bq  = (const float*)d_in[3];
    const float* Wk  = (const float*)d_in[4];
    const float* bk  = (const float*)d_in[5];
    const float* Wv  = (const float*)d_in[6];
    const float* bv  = (const float*)d_in[7];
    const float* Wo  = (const float*)d_in[8];
    const float* bo  = (const float*)d_in[9];
    float* out = (float*)d_out;

    const size_t qkv_elems = (size_t)NB * NH * NN * HDIM;   // 4,194,304
    unsigned short* xt    = (unsigned short*)d_ws;           // x tiled; reused as aot
    unsigned short* q     = xt   + qkv_elems;
    unsigned short* kb    = q    + qkv_elems;
    unsigned short* vtb   = kb   + qkv_elems;
    unsigned short* tWqkv = vtb  + qkv_elems;                // 1536x512 tiled
    unsigned short* tWo   = tWqkv + (size_t)3 * DD * NOUT;   // 512x512 tiled
    unsigned int*   amaskW = (unsigned int*)(tWo + (size_t)DD * NOUT);  // 8MB
    unsigned short* aot   = xt;                              // alias (xt dead after QKV)

    prep<<<dim3(4352), 256, 0, stream>>>(x, xt, Wq, Wk, Wv, Wo,
                                         tWqkv, tWo, adj, amaskW);

    gemm_qkv<<<dim3(12, 64), 256, 0, stream>>>(xt, tWqkv, bq, bk, bv, q, kb, vtb);

    attn_mfma<<<dim3(NN / 128, NH, NB), 512, 0, stream>>>(q, kb, vtb, amaskW, aot);

    gemm_o<<<dim3(8, 64), 256, 0, stream>>>(aot, tWo, bo, out);
}